// Round 16
// baseline (97.051 us; speedup 1.0000x reference)
//
#include <hip/hip_runtime.h>
#include <hip/hip_fp16.h>

typedef _Float16 f16x8 __attribute__((ext_vector_type(8)));
typedef __fp16   fp16x2 __attribute__((ext_vector_type(2)));   // cvt_pkrtz return type
typedef float f32x4 __attribute__((ext_vector_type(4)));

#define FEAT 44
#define TED  84
#define MT   128     // nodes per tile (block)
#define WN   32      // nodes per wave
#define NBLK 768     // persistent blocks
#define BUFB 6144    // per-wave staging buffer bytes (attr 5632; A1 [0,4096), A2 [4096,6144))
#define TB_OFF 49152 // swish table offset in LDS
#define TB_N   4096  // table entries, range [-16,16), step 1/128

// ---------------- kernel 1: merged prep + swish-table build ----------------
__global__ void prep_all(const float* __restrict__ t_arr, const float* __restrict__ W_f,
                         const float* __restrict__ embed_w, const float* __restrict__ embed_b,
                         const float* __restrict__ w0, const float* __restrict__ b0,
                         const float* __restrict__ w1, const float* __restrict__ w2,
                         const int* __restrict__ gptr, int* __restrict__ seg, int do_seg,
                         float* __restrict__ emb0, float* __restrict__ inv_std,
                         _Float16* __restrict__ w0h, _Float16* __restrict__ w1h,
                         _Float16* __restrict__ w2h, float* __restrict__ tb_g, int B) {
    int g   = blockIdx.x;
    int tid = threadIdx.x;
    if (g == B) {   // weight repack block
        for (int i = tid; i < 64 * 64; i += 128) {
            int o = i >> 6, k = i & 63;
            w0h[i] = (k < FEAT) ? (_Float16)w0[o * 128 + k] : (_Float16)0.f;
        }
        for (int i = tid; i < 32 * 64; i += 128) w1h[i] = (_Float16)w1[i];
        for (int i = tid; i < 16 * 32; i += 128) w2h[i] = (i < 4 * 32) ? (_Float16)w2[i] : (_Float16)0.f;
        return;
    }
    if (g == B + 1) {   // swish table: entry i centers x=(i+0.5)/128-16, f32-precise
        for (int i = tid; i < TB_N; i += 128) {
            float x = (i + 0.5f) * (1.0f / 128.0f) - 16.0f;
            tb_g[i] = x / (1.0f + expf(-x));
        }
        return;
    }
    if (do_seg) {
        int a = gptr[g], b = gptr[g + 1];
        for (int i = a + tid; i < b; i += 128) seg[i] = g;
    }
    __shared__ float temb[TED];
    __shared__ float ses[TED];
    float tv = t_arr[g];
    if (tid < TED) {
        int j   = (tid < TED / 2) ? tid : tid - TED / 2;
        float x = tv * W_f[j] * 6.283185307179586f;
        temb[tid] = (tid < TED / 2) ? sinf(x) : cosf(x);
    }
    __syncthreads();
    if (tid < TED) {
        const float* wr = embed_w + tid * TED;
        float s = embed_b[tid];
        #pragma unroll 4
        for (int j = 0; j < TED; ++j) s = fmaf(temb[j], wr[j], s);
        ses[tid] = s / (1.0f + __expf(-s));
    }
    if (tid == TED) {
        const float c = 6.437751649736401f;      // 2*ln(25)
        inv_std[g] = rsqrtf(expm1f(c * tv) / c);
    }
    __syncthreads();
    if (tid < 64) {
        const float* wr = w0 + tid * 128 + FEAT;   // w0[tid][44..127]
        float s = b0[tid];
        #pragma unroll 4
        for (int j = 0; j < TED; ++j) s = fmaf(ses[j], wr[j], s);
        emb0[g * 64 + tid] = s;
    }
}

// ---------------- kernel 2: persistent fused MLP; table-based hidden swish ----------------
__device__ __forceinline__ float swishf(float x) {   // precise (output layer only)
    float e = __builtin_amdgcn_exp2f(x * -1.4426950408889634f);
    return x * __builtin_amdgcn_rcpf(1.0f + e);
}

// table swish: byte idx = clamp(x*512 + 8192) & ~3; full-rate VALU + ds_read_b32
__device__ __forceinline__ float tswish(const char* __restrict__ tb, float x) {
    float fi = fmaf(x, 512.0f, 8192.0f);
    fi = fminf(fmaxf(fi, 0.0f), 16383.0f);
    unsigned a = (unsigned)fi & ~3u;
    return *(const float*)(tb + a);
}

__device__ __forceinline__ int ubound(const int* __restrict__ p, int n, int v) {
    int lo = 0, hi = n;
    while (lo < hi) { int m = (lo + hi) >> 1; if (p[m] <= v) lo = m + 1; else hi = m; }
    return lo - 1;
}

// 6 x global_load_lds(16B): stages 6144B (5632 valid) of node_attr.
__device__ __forceinline__ void stage_attr(const float* __restrict__ node_attr, int row0,
                                           const char* lim, char* dst, int lane) {
    const char* g = (const char*)node_attr + (size_t)row0 * (FEAT * 4);
    #pragma unroll
    for (int k = 0; k < 6; ++k) {
        const char* s = g + k * 1024 + lane * 16;
        if (s > lim) s = lim;                     // clamp: pad lanes read safe bytes
        __builtin_amdgcn_global_load_lds(
            (const __attribute__((address_space(1))) unsigned int*)s,
            (__attribute__((address_space(3))) unsigned int*)(dst + k * 1024),
            16, 0, 0);
    }
}

template<bool USE_SEG>
__global__ __launch_bounds__(256)
void scorenet_main(const float* __restrict__ node_attr,
                   const int* __restrict__ gptr, int B,
                   const int* __restrict__ seg_arr,
                   const float* __restrict__ emb0,
                   const float* __restrict__ inv_std_g,
                   const _Float16* __restrict__ w0h,
                   const _Float16* __restrict__ w1h,
                   const _Float16* __restrict__ w2h,
                   const float* __restrict__ b1,
                   const float* __restrict__ b2,
                   const float* __restrict__ tb_g,
                   float* __restrict__ out, int ntiles, int nbytes_attr) {
    __shared__ __align__(16) char lds[65536];   // 48KB wave buffers + 16KB swish table

    const int t    = threadIdx.x;
    const int lane = t & 63;
    const int wid  = t >> 6;
    const int lr   = lane & 15;
    const int lk   = lane >> 4;
    const char* lim = (const char*)node_attr + nbytes_attr - 16;
    const char* const tb = lds + TB_OFF;

    if (blockIdx.x >= ntiles) return;
    const int stride = gridDim.x;

    // ---- stage swish table (each wave 4KB) ----
    #pragma unroll
    for (int k = 0; k < 4; ++k) {
        const char* s = (const char*)tb_g + wid * 4096 + k * 1024 + lane * 16;
        __builtin_amdgcn_global_load_lds(
            (const __attribute__((address_space(1))) unsigned int*)s,
            (__attribute__((address_space(3))) unsigned int*)(lds + TB_OFF + wid * 4096 + k * 1024),
            16, 0, 0);
    }

    // ---- tile-invariant weights resident ----
    f16x8 aw0[2][4];                          // [kt][mt], A row = out-feat mt*16+lr
    #pragma unroll
    for (int kt = 0; kt < 2; ++kt)
        #pragma unroll
        for (int mt = 0; mt < 4; ++mt)
            aw0[kt][mt] = *(const f16x8*)(w0h + (mt * 16 + lr) * 64 + kt * 32 + lk * 8);
    f16x8 aw1[2][2];
    #pragma unroll
    for (int kt = 0; kt < 2; ++kt)
        #pragma unroll
        for (int mt = 0; mt < 2; ++mt)
            aw1[kt][mt] = *(const f16x8*)(w1h + (mt * 16 + lr) * 64 + kt * 32 + lk * 8);
    f16x8 aw2 = *(const f16x8*)(w2h + lr * 32 + lk * 8);
    f32x4 bias1f[2];
    #pragma unroll
    for (int mt = 0; mt < 2; ++mt) {
        float4 bv = *(const float4*)(b1 + mt * 16 + lk * 4);
        bias1f[mt] = f32x4{bv.x, bv.y, bv.z, bv.w};
    }
    float4 b2vv = *(const float4*)b2;
    const f32x4 c2init = (lk == 0) ? f32x4{b2vv.x, b2vv.y, b2vv.z, b2vv.w} : f32x4{0.f, 0.f, 0.f, 0.f};

    char* buf_cur = lds + wid * (2 * BUFB);
    char* buf_nxt = buf_cur + BUFB;

    int tile = blockIdx.x;

    // ---- prologue: stage tile0; seg for tile0 AND tile1 (depth-2) ----
    stage_attr(node_attr, tile * MT + wid * WN, lim, buf_cur, lane);
    int s0, s1, n0, n1;
    {
        int wb = tile * MT + wid * WN;
        if (USE_SEG) { s0 = seg_arr[wb + lr]; s1 = seg_arr[wb + 16 + lr]; }
        else { s0 = ubound(gptr, B + 1, wb + lr); s1 = ubound(gptr, B + 1, wb + 16 + lr); }
        int t1 = tile + stride; if (t1 >= ntiles) t1 = tile;
        int wb1 = t1 * MT + wid * WN;
        if (USE_SEG) { n0 = seg_arr[wb1 + lr]; n1 = seg_arr[wb1 + 16 + lr]; }
        else { n0 = ubound(gptr, B + 1, wb1 + lr); n1 = ubound(gptr, B + 1, wb1 + 16 + lr); }
    }
    __syncthreads();   // one-time: table fully staged (drains all VMEM incl. tile0 stage)

    while (tile < ntiles) {
        const int wb = tile * MT + wid * WN;
        int tp1 = tile + stride;     if (tp1 >= ntiles) tp1 = tile;
        int tp2 = tile + 2 * stride; if (tp2 >= ntiles) tp2 = tile;

        // ---- A: current tile gathers (10 VMEM); seg resident since 2 iters ago ----
        float is0 = inv_std_g[s0];
        float is1 = inv_std_g[s1];
        f32x4 acc0[4][2];
        #pragma unroll
        for (int mt = 0; mt < 4; ++mt) {
            acc0[mt][0] = *(const f32x4*)(emb0 + s0 * 64 + mt * 16 + lk * 4);
            acc0[mt][1] = *(const f32x4*)(emb0 + s1 * 64 + mt * 16 + lk * 4);
        }

        // ---- B: stage tile+1 -> buf_nxt (6 VMEM, zero VGPR) ----
        stage_attr(node_attr, tp1 * MT + wid * WN, lim, buf_nxt, lane);

        // ---- C: seg for tile+2 (2 VMEM) ----
        int m0, m1;
        {
            int wb2 = tp2 * MT + wid * WN;
            if (USE_SEG) { m0 = seg_arr[wb2 + lr]; m1 = seg_arr[wb2 + 16 + lr]; }
            else { m0 = ubound(gptr, B + 1, wb2 + lr); m1 = ubound(gptr, B + 1, wb2 + 16 + lr); }
        }

        // ---- guarantee prev stage of buf_cur landed ----
        asm volatile("s_waitcnt vmcnt(20)" ::: "memory");
        __builtin_amdgcn_sched_barrier(0);

        // ---- cvt: this tile's attr from buf_cur (f32) -> L0 B-fragments (f16) ----
        union u8 { fp16x2 h2[4]; f16x8 v; };
        f16x8 bf[2][2];
        #pragma unroll
        for (int nt = 0; nt < 2; ++nt) {
            const float4* rowp = (const float4*)(buf_cur + (nt * 16 + lr) * (FEAT * 4));
            float4 a = rowp[lk * 2];
            float4 b = rowp[lk * 2 + 1];
            float4 c = make_float4(0.f, 0.f, 0.f, 0.f);
            float4 d = make_float4(0.f, 0.f, 0.f, 0.f);
            if (lk == 0) { c = rowp[8]; d = rowp[9]; }        // feats 32..39
            else if (lk == 1) { c = rowp[10]; }               // feats 40..43 (44..47 zero)
            u8 f0, f1;
            f0.h2[0] = __builtin_amdgcn_cvt_pkrtz(a.x, a.y);
            f0.h2[1] = __builtin_amdgcn_cvt_pkrtz(a.z, a.w);
            f0.h2[2] = __builtin_amdgcn_cvt_pkrtz(b.x, b.y);
            f0.h2[3] = __builtin_amdgcn_cvt_pkrtz(b.z, b.w);
            f1.h2[0] = __builtin_amdgcn_cvt_pkrtz(c.x, c.y);
            f1.h2[1] = __builtin_amdgcn_cvt_pkrtz(c.z, c.w);
            f1.h2[2] = __builtin_amdgcn_cvt_pkrtz(d.x, d.y);
            f1.h2[3] = __builtin_amdgcn_cvt_pkrtz(d.z, d.w);
            bf[nt][0] = f0.v;
            bf[nt][1] = f1.v;
        }

        // ---- layer 0: D^T[64 out][32 nodes], K=64, C-init = emb0 ----
        #pragma unroll
        for (int kt = 0; kt < 2; ++kt)
            #pragma unroll
            for (int mt = 0; mt < 4; ++mt)
                #pragma unroll
                for (int nt = 0; nt < 2; ++nt)
                    acc0[mt][nt] = __builtin_amdgcn_mfma_f32_16x16x32_f16(aw0[kt][mt], bf[nt][kt], acc0[mt][nt], 0, 0, 0);

        // ---- epilogue 0 -> A1 in buf_cur [0,4096); TABLE swish ----
        #pragma unroll
        for (int mt = 0; mt < 4; ++mt)
            #pragma unroll
            for (int nt = 0; nt < 2; ++nt) {
                int j = nt * 16 + lr;
                union { fp16x2 h2[2]; uint2 u; } p;
                p.h2[0] = __builtin_amdgcn_cvt_pkrtz(tswish(tb, acc0[mt][nt][0]), tswish(tb, acc0[mt][nt][1]));
                p.h2[1] = __builtin_amdgcn_cvt_pkrtz(tswish(tb, acc0[mt][nt][2]), tswish(tb, acc0[mt][nt][3]));
                int addr = j * 128 + (mt * 16 + lk * 4) * 2;
                *(uint2*)(buf_cur + (addr ^ ((j & 7) << 4))) = p.u;
            }

        // ---- layer 1: D^T[32 out][32 nodes], K=64, C-init = b1 ----
        f32x4 acc1[2][2];
        #pragma unroll
        for (int mt = 0; mt < 2; ++mt) { acc1[mt][0] = bias1f[mt]; acc1[mt][1] = bias1f[mt]; }
        #pragma unroll
        for (int kt = 0; kt < 2; ++kt) {
            f16x8 bx[2];
            #pragma unroll
            for (int nt = 0; nt < 2; ++nt) {
                int j    = nt * 16 + lr;
                int addr = j * 128 + kt * 64 + lk * 16;
                bx[nt] = *(const f16x8*)(buf_cur + (addr ^ ((j & 7) << 4)));
            }
            #pragma unroll
            for (int mt = 0; mt < 2; ++mt)
                #pragma unroll
                for (int nt = 0; nt < 2; ++nt)
                    acc1[mt][nt] = __builtin_amdgcn_mfma_f32_16x16x32_f16(aw1[kt][mt], bx[nt], acc1[mt][nt], 0, 0, 0);
        }

        // ---- epilogue 1 -> A2 in buf_cur [4096,6144), 64B rows; TABLE swish ----
        #pragma unroll
        for (int mt = 0; mt < 2; ++mt)
            #pragma unroll
            for (int nt = 0; nt < 2; ++nt) {
                int j = nt * 16 + lr;
                union { fp16x2 h2[2]; uint2 u; } p;
                p.h2[0] = __builtin_amdgcn_cvt_pkrtz(tswish(tb, acc1[mt][nt][0]), tswish(tb, acc1[mt][nt][1]));
                p.h2[1] = __builtin_amdgcn_cvt_pkrtz(tswish(tb, acc1[mt][nt][2]), tswish(tb, acc1[mt][nt][3]));
                int addr = 4096 + j * 64 + (mt * 16 + lk * 4) * 2;
                *(uint2*)(buf_cur + (addr ^ ((j & 3) << 4))) = p.u;
            }

        // ---- layer 2 + direct global store (precise swish: output precision) ----
        f32x4 acc2[2] = {c2init, c2init};
        #pragma unroll
        for (int nt = 0; nt < 2; ++nt) {
            int j    = nt * 16 + lr;
            int addr = 4096 + j * 64 + lk * 16;
            f16x8 bx = *(const f16x8*)(buf_cur + (addr ^ ((j & 3) << 4)));
            acc2[nt] = __builtin_amdgcn_mfma_f32_16x16x32_f16(aw2, bx, acc2[nt], 0, 0, 0);
        }
        if (lk == 0) {
            #pragma unroll
            for (int nt = 0; nt < 2; ++nt) {
                int j = nt * 16 + lr;
                float is = nt ? is1 : is0;
                float4 o;
                o.x = swishf(acc2[nt][0]) * is;
                o.y = swishf(acc2[nt][1]) * is;
                o.z = swishf(acc2[nt][2]) * is;
                o.w = swishf(acc2[nt][3]) * is;
                *(float4*)(out + (size_t)(wb + j) * 4) = o;
            }
        }

        // ---- rotate pipeline ----
        { char* tmp = buf_cur; buf_cur = buf_nxt; buf_nxt = tmp; }
        s0 = n0; s1 = n1; n0 = m0; n1 = m1;
        tile += stride;
    }
}

// ---------------- launch ----------------
extern "C" void kernel_launch(void* const* d_in, const int* in_sizes, int n_in,
                              void* d_out, int out_size, void* d_ws, size_t ws_size,
                              hipStream_t stream) {
    const float* node_attr = (const float*)d_in[0];
    const float* t_arr     = (const float*)d_in[1];
    const int*   gptr      = (const int*)d_in[2];
    const float* W_f       = (const float*)d_in[3];
    const float* embed_w   = (const float*)d_in[4];
    const float* embed_b   = (const float*)d_in[5];
    const float* w0        = (const float*)d_in[6];
    const float* b0        = (const float*)d_in[7];
    const float* w1        = (const float*)d_in[8];
    const float* b1        = (const float*)d_in[9];
    const float* w2        = (const float*)d_in[10];
    const float* b2        = (const float*)d_in[11];
    float* out = (float*)d_out;

    const int N = in_sizes[0] / FEAT;
    const int B = in_sizes[2] - 1;
    const int ntiles = N / MT;
    const int nbytes_attr = in_sizes[0] * 4;

    char* ws = (char*)d_ws;
    size_t off = 0;
    float*    emb0    = (float*)(ws + off); off += (size_t)B * 64 * sizeof(float);
    off = (off + 1023) & ~(size_t)1023;
    float*    inv_std = (float*)(ws + off); off += (size_t)B * sizeof(float);
    off = (off + 1023) & ~(size_t)1023;
    _Float16* w0h = (_Float16*)(ws + off);  off += 64 * 64 * sizeof(_Float16);
    _Float16* w1h = (_Float16*)(ws + off);  off += 32 * 64 * sizeof(_Float16);
    _Float16* w2h = (_Float16*)(ws + off);  off += 16 * 32 * sizeof(_Float16);
    off = (off + 1023) & ~(size_t)1023;
    float* tb_g = (float*)(ws + off);       off += TB_N * sizeof(float);
    off = (off + 1023) & ~(size_t)1023;
    int* seg = (int*)(ws + off);
    size_t need_with_seg = off + (size_t)N * sizeof(int);
    bool use_seg = (ws_size >= need_with_seg);

    const int grid = (ntiles < NBLK) ? ntiles : NBLK;

    prep_all<<<B + 2, 128, 0, stream>>>(t_arr, W_f, embed_w, embed_b, w0, b0, w1, w2,
                                        gptr, seg, use_seg ? 1 : 0,
                                        emb0, inv_std, w0h, w1h, w2h, tb_g, B);
    if (use_seg) {
        scorenet_main<true><<<grid, 256, 0, stream>>>(node_attr, gptr, B, seg, emb0, inv_std,
                                                      w0h, w1h, w2h, b1, b2, tb_g, out, ntiles, nbytes_attr);
    } else {
        scorenet_main<false><<<grid, 256, 0, stream>>>(node_attr, gptr, B, seg, emb0, inv_std,
                                                       w0h, w1h, w2h, b1, b2, tb_g, out, ntiles, nbytes_attr);
    }
}

// Round 17
// 85.614 us; speedup vs baseline: 1.1336x; 1.1336x over previous
//
#include <hip/hip_runtime.h>
#include <hip/hip_fp16.h>

typedef _Float16 f16x8 __attribute__((ext_vector_type(8)));
typedef __fp16   fp16x2 __attribute__((ext_vector_type(2)));   // cvt_pkrtz return type
typedef float f32x4 __attribute__((ext_vector_type(4)));

#define FEAT 44
#define TED  84
#define MT   128      // nodes per tile (block)
#define WN   32       // nodes per wave
#define NBLK 512      // persistent blocks (2 per CU at 64KB LDS)
#define BUFB 6144     // per-wave attr buffer bytes (5632 valid)
#define WSLICE 16384  // per-wave LDS slice: buf0, buf1, work(A1 4KB; A2 overlaps first 2KB)
#define WORK_OFF 12288

// ---------------- kernel 1: merged prep (R12 form) ----------------
__global__ void prep_all(const float* __restrict__ t_arr, const float* __restrict__ W_f,
                         const float* __restrict__ embed_w, const float* __restrict__ embed_b,
                         const float* __restrict__ w0, const float* __restrict__ b0,
                         const float* __restrict__ w1, const float* __restrict__ w2,
                         const int* __restrict__ gptr, int* __restrict__ seg, int do_seg,
                         float* __restrict__ emb0, float* __restrict__ inv_std,
                         _Float16* __restrict__ w0h, _Float16* __restrict__ w1h,
                         _Float16* __restrict__ w2h, int B) {
    int g   = blockIdx.x;
    int tid = threadIdx.x;
    if (g == B) {   // weight repack block
        for (int i = tid; i < 64 * 64; i += 128) {
            int o = i >> 6, k = i & 63;
            w0h[i] = (k < FEAT) ? (_Float16)w0[o * 128 + k] : (_Float16)0.f;
        }
        for (int i = tid; i < 32 * 64; i += 128) w1h[i] = (_Float16)w1[i];
        for (int i = tid; i < 16 * 32; i += 128) w2h[i] = (i < 4 * 32) ? (_Float16)w2[i] : (_Float16)0.f;
        return;
    }
    if (do_seg) {
        int a = gptr[g], b = gptr[g + 1];
        for (int i = a + tid; i < b; i += 128) seg[i] = g;
    }
    __shared__ float temb[TED];
    __shared__ float ses[TED];
    float tv = t_arr[g];
    if (tid < TED) {
        int j   = (tid < TED / 2) ? tid : tid - TED / 2;
        float x = tv * W_f[j] * 6.283185307179586f;
        temb[tid] = (tid < TED / 2) ? sinf(x) : cosf(x);
    }
    __syncthreads();
    if (tid < TED) {
        const float* wr = embed_w + tid * TED;
        float s = embed_b[tid];
        #pragma unroll 4
        for (int j = 0; j < TED; ++j) s = fmaf(temb[j], wr[j], s);
        ses[tid] = s / (1.0f + __expf(-s));
    }
    if (tid == TED) {
        const float c = 6.437751649736401f;      // 2*ln(25)
        inv_std[g] = rsqrtf(expm1f(c * tv) / c);
    }
    __syncthreads();
    if (tid < 64) {
        const float* wr = w0 + tid * 128 + FEAT;   // w0[tid][44..127]
        float s = b0[tid];
        #pragma unroll 4
        for (int j = 0; j < TED; ++j) s = fmaf(ses[j], wr[j], s);
        emb0[g * 64 + tid] = s;
    }
}

// ---------------- kernel 2: persistent fused MLP, split-phase pipeline ----------------
__device__ __forceinline__ float swishf(float x) {
    float e = __builtin_amdgcn_exp2f(x * -1.4426950408889634f);
    return x * __builtin_amdgcn_rcpf(1.0f + e);
}

__device__ __forceinline__ int ubound(const int* __restrict__ p, int n, int v) {
    int lo = 0, hi = n;
    while (lo < hi) { int m = (lo + hi) >> 1; if (p[m] <= v) lo = m + 1; else hi = m; }
    return lo - 1;
}

// 6 x global_load_lds(16B): stages 6144B (5632 valid) of node_attr.
__device__ __forceinline__ void stage_attr(const float* __restrict__ node_attr, int row0,
                                           const char* lim, char* dst, int lane) {
    const char* g = (const char*)node_attr + (size_t)row0 * (FEAT * 4);
    #pragma unroll
    for (int k = 0; k < 6; ++k) {
        const char* s = g + k * 1024 + lane * 16;
        if (s > lim) s = lim;                     // clamp: pad lanes read safe bytes
        __builtin_amdgcn_global_load_lds(
            (const __attribute__((address_space(1))) unsigned int*)s,
            (__attribute__((address_space(3))) unsigned int*)(dst + k * 1024),
            16, 0, 0);
    }
}

// back-half of one tile: ep0 -> A1, L1, ep1 -> A2 (overlaps A1 head), L2, store.
__device__ __forceinline__ void back_half(const f32x4 (*accp)[2], float isp0, float isp1,
                                          int wbp, char* work, float* __restrict__ out,
                                          const f16x8 (*aw1)[2], f16x8 aw2,
                                          const f32x4* bias1f, f32x4 c2init,
                                          int lr, int lk) {
    // ---- epilogue 0 -> A1 [0,4096), rows j*128, swz ^((j&7)<<4) ----
    #pragma unroll
    for (int mt = 0; mt < 4; ++mt)
        #pragma unroll
        for (int nt = 0; nt < 2; ++nt) {
            int j = nt * 16 + lr;
            union { fp16x2 h2[2]; uint2 u; } p;
            p.h2[0] = __builtin_amdgcn_cvt_pkrtz(swishf(accp[mt][nt][0]), swishf(accp[mt][nt][1]));
            p.h2[1] = __builtin_amdgcn_cvt_pkrtz(swishf(accp[mt][nt][2]), swishf(accp[mt][nt][3]));
            int addr = j * 128 + (mt * 16 + lk * 4) * 2;
            *(uint2*)(work + (addr ^ ((j & 7) << 4))) = p.u;
        }
    // ---- layer 1: D^T[32 out][32 nodes], K=64, C-init = b1 ----
    f32x4 acc1[2][2];
    #pragma unroll
    for (int mt = 0; mt < 2; ++mt) { acc1[mt][0] = bias1f[mt]; acc1[mt][1] = bias1f[mt]; }
    #pragma unroll
    for (int kt = 0; kt < 2; ++kt) {
        f16x8 bx[2];
        #pragma unroll
        for (int nt = 0; nt < 2; ++nt) {
            int j    = nt * 16 + lr;
            int addr = j * 128 + kt * 64 + lk * 16;
            bx[nt] = *(const f16x8*)(work + (addr ^ ((j & 7) << 4)));
        }
        #pragma unroll
        for (int mt = 0; mt < 2; ++mt)
            #pragma unroll
            for (int nt = 0; nt < 2; ++nt)
                acc1[mt][nt] = __builtin_amdgcn_mfma_f32_16x16x32_f16(aw1[kt][mt], bx[nt], acc1[mt][nt], 0, 0, 0);
    }
    // ---- epilogue 1 -> A2 [0,2048) (A1 fully consumed), rows j*64, swz ^((j&3)<<4) ----
    #pragma unroll
    for (int mt = 0; mt < 2; ++mt)
        #pragma unroll
        for (int nt = 0; nt < 2; ++nt) {
            int j = nt * 16 + lr;
            union { fp16x2 h2[2]; uint2 u; } p;
            p.h2[0] = __builtin_amdgcn_cvt_pkrtz(swishf(acc1[mt][nt][0]), swishf(acc1[mt][nt][1]));
            p.h2[1] = __builtin_amdgcn_cvt_pkrtz(swishf(acc1[mt][nt][2]), swishf(acc1[mt][nt][3]));
            int addr = j * 64 + (mt * 16 + lk * 4) * 2;
            *(uint2*)(work + (addr ^ ((j & 3) << 4))) = p.u;
        }
    // ---- layer 2 + direct global store ----
    f32x4 acc2[2] = {c2init, c2init};
    #pragma unroll
    for (int nt = 0; nt < 2; ++nt) {
        int j    = nt * 16 + lr;
        int addr = j * 64 + lk * 16;
        f16x8 bx = *(const f16x8*)(work + (addr ^ ((j & 3) << 4)));
        acc2[nt] = __builtin_amdgcn_mfma_f32_16x16x32_f16(aw2, bx, acc2[nt], 0, 0, 0);
    }
    if (lk == 0) {
        #pragma unroll
        for (int nt = 0; nt < 2; ++nt) {
            int j = nt * 16 + lr;
            float is = nt ? isp1 : isp0;
            float4 o;
            o.x = swishf(acc2[nt][0]) * is;
            o.y = swishf(acc2[nt][1]) * is;
            o.z = swishf(acc2[nt][2]) * is;
            o.w = swishf(acc2[nt][3]) * is;
            *(float4*)(out + (size_t)(wbp + j) * 4) = o;
        }
    }
}

template<bool USE_SEG>
__global__ __launch_bounds__(256)
void scorenet_main(const float* __restrict__ node_attr,
                   const int* __restrict__ gptr, int B,
                   const int* __restrict__ seg_arr,
                   const float* __restrict__ emb0,
                   const float* __restrict__ inv_std_g,
                   const _Float16* __restrict__ w0h,
                   const _Float16* __restrict__ w1h,
                   const _Float16* __restrict__ w2h,
                   const float* __restrict__ b1,
                   const float* __restrict__ b2,
                   float* __restrict__ out, int ntiles, int nbytes_attr) {
    __shared__ __align__(16) char lds[65536];

    const int t    = threadIdx.x;
    const int lane = t & 63;
    const int wid  = t >> 6;
    const int lr   = lane & 15;
    const int lk   = lane >> 4;
    const char* lim = (const char*)node_attr + nbytes_attr - 16;

    if (blockIdx.x >= ntiles) return;
    const int stride = gridDim.x;

    // ---- tile-invariant weights resident ----
    f16x8 aw0[2][4];                          // [kt][mt], A row = out-feat mt*16+lr
    #pragma unroll
    for (int kt = 0; kt < 2; ++kt)
        #pragma unroll
        for (int mt = 0; mt < 4; ++mt)
            aw0[kt][mt] = *(const f16x8*)(w0h + (mt * 16 + lr) * 64 + kt * 32 + lk * 8);
    f16x8 aw1[2][2];
    #pragma unroll
    for (int kt = 0; kt < 2; ++kt)
        #pragma unroll
        for (int mt = 0; mt < 2; ++mt)
            aw1[kt][mt] = *(const f16x8*)(w1h + (mt * 16 + lr) * 64 + kt * 32 + lk * 8);
    f16x8 aw2 = *(const f16x8*)(w2h + lr * 32 + lk * 8);
    f32x4 bias1f[2];
    #pragma unroll
    for (int mt = 0; mt < 2; ++mt) {
        float4 bv = *(const float4*)(b1 + mt * 16 + lk * 4);
        bias1f[mt] = f32x4{bv.x, bv.y, bv.z, bv.w};
    }
    float4 b2vv = *(const float4*)b2;
    const f32x4 c2init = (lk == 0) ? f32x4{b2vv.x, b2vv.y, b2vv.z, b2vv.w} : f32x4{0.f, 0.f, 0.f, 0.f};

    char* base    = lds + wid * WSLICE;
    char* buf_cur = base;
    char* buf_nxt = base + BUFB;
    char* const work = base + WORK_OFF;

    int tile = blockIdx.x;

    // ---- prologue: stage(f0); seg(f0), seg(f1) ----
    stage_attr(node_attr, tile * MT + wid * WN, lim, buf_cur, lane);
    int s0, s1, n0, n1;
    {
        int wb = tile * MT + wid * WN;
        if (USE_SEG) { s0 = seg_arr[wb + lr]; s1 = seg_arr[wb + 16 + lr]; }
        else { s0 = ubound(gptr, B + 1, wb + lr); s1 = ubound(gptr, B + 1, wb + 16 + lr); }
        int t1 = tile + stride; if (t1 >= ntiles) t1 = tile;
        int wb1 = t1 * MT + wid * WN;
        if (USE_SEG) { n0 = seg_arr[wb1 + lr]; n1 = seg_arr[wb1 + 16 + lr]; }
        else { n0 = ubound(gptr, B + 1, wb1 + lr); n1 = ubound(gptr, B + 1, wb1 + 16 + lr); }
    }

    // ---- pipeline state ----
    f32x4 acc_p[4][2];
    float isp0, isp1;
    int wbp;

    // ---- prologue front(f0): gathers, stage(f1), seg(f2), cvt+L0 ----
    {
        wbp  = tile * MT + wid * WN;
        isp0 = inv_std_g[s0];
        isp1 = inv_std_g[s1];
        #pragma unroll
        for (int mt = 0; mt < 4; ++mt) {
            acc_p[mt][0] = *(const f32x4*)(emb0 + s0 * 64 + mt * 16 + lk * 4);
            acc_p[mt][1] = *(const f32x4*)(emb0 + s1 * 64 + mt * 16 + lk * 4);
        }
        int t1 = tile + stride;     if (t1 >= ntiles) t1 = tile;
        stage_attr(node_attr, t1 * MT + wid * WN, lim, buf_nxt, lane);
        int t2 = tile + 2 * stride; if (t2 >= ntiles) t2 = tile;
        int wb2 = t2 * MT + wid * WN;
        int m0, m1;
        if (USE_SEG) { m0 = seg_arr[wb2 + lr]; m1 = seg_arr[wb2 + 16 + lr]; }
        else { m0 = ubound(gptr, B + 1, wb2 + lr); m1 = ubound(gptr, B + 1, wb2 + 16 + lr); }

        if (USE_SEG) { asm volatile("s_waitcnt vmcnt(22)" ::: "memory"); }
        else         { asm volatile("s_waitcnt vmcnt(0)"  ::: "memory"); }
        __builtin_amdgcn_sched_barrier(0);

        union u8 { fp16x2 h2[4]; f16x8 v; };
        f16x8 bf[2][2];
        #pragma unroll
        for (int nt = 0; nt < 2; ++nt) {
            const float4* rowp = (const float4*)(buf_cur + (nt * 16 + lr) * (FEAT * 4));
            float4 a = rowp[lk * 2];
            float4 b = rowp[lk * 2 + 1];
            float4 c = make_float4(0.f, 0.f, 0.f, 0.f);
            float4 d = make_float4(0.f, 0.f, 0.f, 0.f);
            if (lk == 0) { c = rowp[8]; d = rowp[9]; }
            else if (lk == 1) { c = rowp[10]; }
            u8 f0, f1;
            f0.h2[0] = __builtin_amdgcn_cvt_pkrtz(a.x, a.y);
            f0.h2[1] = __builtin_amdgcn_cvt_pkrtz(a.z, a.w);
            f0.h2[2] = __builtin_amdgcn_cvt_pkrtz(b.x, b.y);
            f0.h2[3] = __builtin_amdgcn_cvt_pkrtz(b.z, b.w);
            f1.h2[0] = __builtin_amdgcn_cvt_pkrtz(c.x, c.y);
            f1.h2[1] = __builtin_amdgcn_cvt_pkrtz(c.z, c.w);
            f1.h2[2] = __builtin_amdgcn_cvt_pkrtz(d.x, d.y);
            f1.h2[3] = __builtin_amdgcn_cvt_pkrtz(d.z, d.w);
            bf[nt][0] = f0.v;
            bf[nt][1] = f1.v;
        }
        #pragma unroll
        for (int kt = 0; kt < 2; ++kt)
            #pragma unroll
            for (int mt = 0; mt < 4; ++mt)
                #pragma unroll
                for (int nt = 0; nt < 2; ++nt)
                    acc_p[mt][nt] = __builtin_amdgcn_mfma_f32_16x16x32_f16(aw0[kt][mt], bf[nt][kt], acc_p[mt][nt], 0, 0, 0);

        s0 = n0; s1 = n1; n0 = m0; n1 = m1;
        { char* tmp = buf_cur; buf_cur = buf_nxt; buf_nxt = tmp; }
        tile += stride;
    }

    // ---- steady-state: front(tile) overlapped with back(tile-stride) ----
    while (tile < ntiles) {
        const int wb = tile * MT + wid * WN;

        // 1. gathers for current front tile (10 VMEM)
        float isc0 = inv_std_g[s0];
        float isc1 = inv_std_g[s1];
        f32x4 accC[4][2];
        #pragma unroll
        for (int mt = 0; mt < 4; ++mt) {
            accC[mt][0] = *(const f32x4*)(emb0 + s0 * 64 + mt * 16 + lk * 4);
            accC[mt][1] = *(const f32x4*)(emb0 + s1 * 64 + mt * 16 + lk * 4);
        }

        // 2. stage tile+1 (6 VMEM, zero VGPR)
        int t1 = tile + stride;     if (t1 >= ntiles) t1 = tile;
        stage_attr(node_attr, t1 * MT + wid * WN, lim, buf_nxt, lane);

        // 3. seg tile+2 (2 VMEM)
        int t2 = tile + 2 * stride; if (t2 >= ntiles) t2 = tile;
        int wb2 = t2 * MT + wid * WN;
        int m0, m1;
        if (USE_SEG) { m0 = seg_arr[wb2 + lr]; m1 = seg_arr[wb2 + 16 + lr]; }
        else { m0 = ubound(gptr, B + 1, wb2 + lr); m1 = ubound(gptr, B + 1, wb2 + 16 + lr); }

        // 4. BACK half of previous tile (DS+VALU+MFMA; hides gather/stage latency)
        back_half(acc_p, isp0, isp1, wbp, work, out, aw1, aw2, bias1f, c2init, lr, lk);

        // 5. ensure this front tile's stage (issued last iteration) has landed
        if (USE_SEG) { asm volatile("s_waitcnt vmcnt(22)" ::: "memory"); }
        else         { asm volatile("s_waitcnt vmcnt(0)"  ::: "memory"); }
        __builtin_amdgcn_sched_barrier(0);

        // 6. cvt + layer 0 for current front tile
        union u8 { fp16x2 h2[4]; f16x8 v; };
        f16x8 bf[2][2];
        #pragma unroll
        for (int nt = 0; nt < 2; ++nt) {
            const float4* rowp = (const float4*)(buf_cur + (nt * 16 + lr) * (FEAT * 4));
            float4 a = rowp[lk * 2];
            float4 b = rowp[lk * 2 + 1];
            float4 c = make_float4(0.f, 0.f, 0.f, 0.f);
            float4 d = make_float4(0.f, 0.f, 0.f, 0.f);
            if (lk == 0) { c = rowp[8]; d = rowp[9]; }
            else if (lk == 1) { c = rowp[10]; }
            u8 f0, f1;
            f0.h2[0] = __builtin_amdgcn_cvt_pkrtz(a.x, a.y);
            f0.h2[1] = __builtin_amdgcn_cvt_pkrtz(a.z, a.w);
            f0.h2[2] = __builtin_amdgcn_cvt_pkrtz(b.x, b.y);
            f0.h2[3] = __builtin_amdgcn_cvt_pkrtz(b.z, b.w);
            f1.h2[0] = __builtin_amdgcn_cvt_pkrtz(c.x, c.y);
            f1.h2[1] = __builtin_amdgcn_cvt_pkrtz(c.z, c.w);
            f1.h2[2] = __builtin_amdgcn_cvt_pkrtz(d.x, d.y);
            f1.h2[3] = __builtin_amdgcn_cvt_pkrtz(d.z, d.w);
            bf[nt][0] = f0.v;
            bf[nt][1] = f1.v;
        }
        #pragma unroll
        for (int kt = 0; kt < 2; ++kt)
            #pragma unroll
            for (int mt = 0; mt < 4; ++mt)
                #pragma unroll
                for (int nt = 0; nt < 2; ++nt)
                    accC[mt][nt] = __builtin_amdgcn_mfma_f32_16x16x32_f16(aw0[kt][mt], bf[nt][kt], accC[mt][nt], 0, 0, 0);

        // rotate pipeline state
        #pragma unroll
        for (int mt = 0; mt < 4; ++mt) { acc_p[mt][0] = accC[mt][0]; acc_p[mt][1] = accC[mt][1]; }
        isp0 = isc0; isp1 = isc1; wbp = wb;
        s0 = n0; s1 = n1; n0 = m0; n1 = m1;
        { char* tmp = buf_cur; buf_cur = buf_nxt; buf_nxt = tmp; }
        tile += stride;
    }

    // ---- epilogue: back-half of the final tile ----
    back_half(acc_p, isp0, isp1, wbp, work, out, aw1, aw2, bias1f, c2init, lr, lk);
}

// ---------------- launch ----------------
extern "C" void kernel_launch(void* const* d_in, const int* in_sizes, int n_in,
                              void* d_out, int out_size, void* d_ws, size_t ws_size,
                              hipStream_t stream) {
    const float* node_attr = (const float*)d_in[0];
    const float* t_arr     = (const float*)d_in[1];
    const int*   gptr      = (const int*)d_in[2];
    const float* W_f       = (const float*)d_in[3];
    const float* embed_w   = (const float*)d_in[4];
    const float* embed_b   = (const float*)d_in[5];
    const float* w0        = (const float*)d_in[6];
    const float* b0        = (const float*)d_in[7];
    const float* w1        = (const float*)d_in[8];
    const float* b1        = (const float*)d_in[9];
    const float* w2        = (const float*)d_in[10];
    const float* b2        = (const float*)d_in[11];
    float* out = (float*)d_out;

    const int N = in_sizes[0] / FEAT;
    const int B = in_sizes[2] - 1;
    const int ntiles = N / MT;
    const int nbytes_attr = in_sizes[0] * 4;

    char* ws = (char*)d_ws;
    size_t off = 0;
    float*    emb0    = (float*)(ws + off); off += (size_t)B * 64 * sizeof(float);
    off = (off + 1023) & ~(size_t)1023;
    float*    inv_std = (float*)(ws + off); off += (size_t)B * sizeof(float);
    off = (off + 1023) & ~(size_t)1023;
    _Float16* w0h = (_Float16*)(ws + off);  off += 64 * 64 * sizeof(_Float16);
    _Float16* w1h = (_Float16*)(ws + off);  off += 32 * 64 * sizeof(_Float16);
    _Float16* w2h = (_Float16*)(ws + off);  off += 16 * 32 * sizeof(_Float16);
    off = (off + 1023) & ~(size_t)1023;
    int* seg = (int*)(ws + off);
    size_t need_with_seg = off + (size_t)N * sizeof(int);
    bool use_seg = (ws_size >= need_with_seg);

    const int grid = (ntiles < NBLK) ? ntiles : NBLK;

    prep_all<<<B + 1, 128, 0, stream>>>(t_arr, W_f, embed_w, embed_b, w0, b0, w1, w2,
                                        gptr, seg, use_seg ? 1 : 0,
                                        emb0, inv_std, w0h, w1h, w2h, B);
    if (use_seg) {
        scorenet_main<true><<<grid, 256, 0, stream>>>(node_attr, gptr, B, seg, emb0, inv_std,
                                                      w0h, w1h, w2h, b1, b2, out, ntiles, nbytes_attr);
    } else {
        scorenet_main<false><<<grid, 256, 0, stream>>>(node_attr, gptr, B, seg, emb0, inv_std,
                                                       w0h, w1h, w2h, b1, b2, out, ntiles, nbytes_attr);
    }
}